// Round 8
// baseline (1091.786 us; speedup 1.0000x reference)
//
#include <hip/hip_runtime.h>
#include <float.h>

#define BATCH 8
#define TPTS 30000
#define NPR 30016             // padded rows per batch (469 * 64)
#define HID 128
#define R2 4096
#define NPTS (BATCH * TPTS)   // 240000
#define PB 64                 // points per block
#define XS 264                // xs row stride in bf16 elems (256 + 8 pad)
#define HS 136                // h row stride (128 + 8 pad)

typedef __attribute__((ext_vector_type(8))) short short8;
typedef __attribute__((ext_vector_type(4))) short short4v;
typedef __attribute__((ext_vector_type(4))) float f32x4;

__device__ __forceinline__ short f2bf(float f) {
    unsigned u = __float_as_uint(f);
    u += 0x7fff + ((u >> 16) & 1);   // RNE
    return (short)(u >> 16);
}
__device__ __forceinline__ float bf2f(unsigned short u) {
    return __uint_as_float(((unsigned)u) << 16);
}
// packed relu on two bf16 in one dword: negative -> sign-only (-0.0, harmless as matmul input)
__device__ __forceinline__ unsigned relu2(unsigned u) {
    unsigned sm = u & 0x80008000u;
    unsigned d  = sm - (sm >> 15);
    return u & ~d;
}
__device__ __forceinline__ short8 relu8(short8 v) {
    union { short8 s; unsigned u[4]; } a;
    a.s = v;
#pragma unroll
    for (int i = 0; i < 4; ++i) a.u[i] = relu2(a.u[i]);
    return a.s;
}

__global__ void k_fill4(float4* p, float v, int n4) {
    int i = blockIdx.x * blockDim.x + threadIdx.x;
    if (i < n4) p[i] = make_float4(v, v, v, v);
}

// ---------- weight prep: f32 [k][ch] -> bf16 transposed [ch][k] ----------
__global__ __launch_bounds__(256) void k_prep(
    const float* __restrict__ fc0w, const float* __restrict__ fc1w, const float* __restrict__ scw,
    const float* __restrict__ fccw,
    short* __restrict__ Wt0, short* __restrict__ Wts, short* __restrict__ Wt1,
    short* __restrict__ Wtc)
{
    int i = blockIdx.x * 256 + threadIdx.x;
    if (i < 5 * 128 * 256) {
        int r = i >> 15;
        int c = (i >> 8) & 127;
        int k = i & 255;
        Wt0[i] = f2bf(fc0w[(r * 256 + k) * 128 + c]);
        Wts[i] = f2bf(scw [(r * 256 + k) * 128 + c]);
    }
    if (i < 5 * 128 * 128) {
        int r = i >> 14;
        int c = (i >> 7) & 127;
        int k = i & 127;
        Wt1[i] = f2bf(fc1w[(r * 128 + k) * 128 + c]);
    }
    if (i < 128 * 128) {
        int c = (i >> 7) & 127;
        int k = i & 127;
        Wtc[i] = f2bf(fccw[k * 128 + c]);
    }
}

// ---------- counting sort of points by bin (per plane, per batch) ----------
__global__ void k_hist(const int* __restrict__ i0, const int* __restrict__ i1,
                       const int* __restrict__ i2, int* __restrict__ hist)
{
    int t = blockIdx.x * 256 + threadIdx.x;
    if (t >= NPTS) return;
    int b = t / TPTS;
    atomicAdd(&hist[(0 * BATCH + b) * R2 + i0[t]], 1);
    atomicAdd(&hist[(1 * BATCH + b) * R2 + i1[t]], 1);
    atomicAdd(&hist[(2 * BATCH + b) * R2 + i2[t]], 1);
}

__global__ __launch_bounds__(256) void k_scan(const int* __restrict__ hist,
                                              int* __restrict__ starts, int* __restrict__ cursor)
{
    int pb = blockIdx.x;                 // 0..23
    const int* h = hist + pb * R2;
    int tid = threadIdx.x;
    __shared__ int part[257];
    int loc[16]; int s = 0;
    int base = tid * 16;
#pragma unroll
    for (int q = 0; q < 16; ++q) { loc[q] = s; s += h[base + q]; }
    part[tid + 1] = s;
    __syncthreads();
    if (tid == 0) {
        part[0] = 0;
        for (int i = 1; i <= 256; ++i) part[i] += part[i - 1];
    }
    __syncthreads();
    int off = part[tid];
#pragma unroll
    for (int q = 0; q < 16; ++q) {
        int v = off + loc[q];
        starts[pb * 4097 + base + q] = v;
        cursor[pb * R2 + base + q] = v;
    }
    if (tid == 255) starts[pb * 4097 + 4096] = part[256];
}

__global__ void k_scatter(const int* __restrict__ i0, const int* __restrict__ i1,
                          const int* __restrict__ i2, int* __restrict__ cursor,
                          unsigned short* __restrict__ order)
{
    int t = blockIdx.x * 256 + threadIdx.x;
    if (t >= NPTS) return;
    int b = t / TPTS;
    int tt = t - b * TPTS;
    int s0 = atomicAdd(&cursor[(0 * BATCH + b) * R2 + i0[t]], 1);
    order[(0 * BATCH + b) * TPTS + s0] = (unsigned short)tt;
    int s1 = atomicAdd(&cursor[(1 * BATCH + b) * R2 + i1[t]], 1);
    order[(1 * BATCH + b) * TPTS + s1] = (unsigned short)tt;
    int s2 = atomicAdd(&cursor[(2 * BATCH + b) * R2 + i2[t]], 1);
    order[(2 * BATCH + b) * TPTS + s2] = (unsigned short)tt;
}

// ---------- gather-based pool max over bf16 net: one wave per bin ----------
// grid (8, 3072): batch = blockIdx.x (XCD affinity), plane/bin from blockIdx.y
__global__ __launch_bounds__(256) void k_poolmax(
    const short* __restrict__ net, const int* __restrict__ starts,
    const unsigned short* __restrict__ order, short* __restrict__ seg)
{
    int b = blockIdx.x;
    int plane = blockIdx.y >> 10;
    int bin = (blockIdx.y & 1023) * 4 + (threadIdx.x >> 6);
    int pb = plane * BATCH + b;
    int lane = threadIdx.x & 63;
    int s = starts[pb * 4097 + bin], e = starts[pb * 4097 + bin + 1];
    if (s == e) return;                       // empty bins never gathered
    const unsigned short* ord = order + pb * TPTS;
    float vx = -FLT_MAX, vy = -FLT_MAX;
    for (int i = s; i < e; ++i) {
        int t = b * NPR + ord[i];
        unsigned u = *(const unsigned*)(net + t * HID + lane * 2);
        vx = fmaxf(vx, bf2f((unsigned short)(u & 0xFFFF)));
        vy = fmaxf(vy, bf2f((unsigned short)(u >> 16)));
    }
    unsigned o = ((unsigned short)f2bf(vx)) | (((unsigned)(unsigned short)f2bf(vy)) << 16);
    *(unsigned*)(seg + (pb * R2 + bin) * HID + lane * 2) = o;
}

// ---------- gather-based pool mean over bf16 net -> bf16 means [pb][bin][128] ----------
__global__ __launch_bounds__(256) void k_poolmean(
    const short* __restrict__ net, const int* __restrict__ starts,
    const unsigned short* __restrict__ order, short* __restrict__ meanb)
{
    int b = blockIdx.x;
    int plane = blockIdx.y >> 10;
    int bin = (blockIdx.y & 1023) * 4 + (threadIdx.x >> 6);
    int pb = plane * BATCH + b;
    int lane = threadIdx.x & 63;
    int s = starts[pb * 4097 + bin], e = starts[pb * 4097 + bin + 1];
    const unsigned short* ord = order + pb * TPTS;
    float vx = 0.f, vy = 0.f;
    for (int i = s; i < e; ++i) {
        int t = b * NPR + ord[i];
        unsigned u = *(const unsigned*)(net + t * HID + lane * 2);
        vx += bf2f((unsigned short)(u & 0xFFFF));
        vy += bf2f((unsigned short)(u >> 16));
    }
    float inv = 1.f / fmaxf((float)(e - s), 1.f);
    unsigned o = ((unsigned short)f2bf(vx * inv)) | (((unsigned)(unsigned short)f2bf(vy * inv)) << 16);
    *(unsigned*)(meanb + (pb * R2 + bin) * HID + lane * 2) = o;   // empty bins -> 0
}

// ---------- resnet body: 8 waves x 16ch, merged S+F phase, coalesced epilogue ----------
// 512 threads. acc = 8 f32x4 per wave -> register headroom for load pipelining.
__device__ __forceinline__ void resnet_body(
    short* xs, const float* b0s, const float* b1s,
    const short* __restrict__ Wt0r, const short* __restrict__ Wtsr,
    const short* __restrict__ Wt1r, short* __restrict__ net_out, int t0)
{
    int tid = threadIdx.x;
    int lane = tid & 63;
    int wave = tid >> 6;        // 0..7
    int n    = lane & 15;
    int quad = lane >> 4;
    int ch0  = wave * 16;       // 16 channels per wave

    // merged phase: accS = x @ wsc ; accF = relu(x) @ w0
    f32x4 accS[4] = {};
    f32x4 accF[4] = {};
    for (int ks = 0; ks < 8; ++ks) {
        int ko = ks * 32 + quad * 8;
        int row = ch0 + n;
        short8 aS = *(const short8*)(Wtsr + row * 256 + ko);
        short8 aF = *(const short8*)(Wt0r + row * 256 + ko);
#pragma unroll
        for (int p = 0; p < 4; ++p) {
            short8 bX = *(const short8*)(xs + (p * 16 + n) * XS + ko);
            short8 bR = relu8(bX);
            accS[p] = __builtin_amdgcn_mfma_f32_16x16x32_bf16(aS, bX, accS[p], 0, 0, 0);
            accF[p] = __builtin_amdgcn_mfma_f32_16x16x32_bf16(aF, bR, accF[p], 0, 0, 0);
        }
    }
    __syncthreads();   // all xs reads done; safe to alias h

    short* h = xs;
    {
        int chb = ch0 + quad * 4;
#pragma unroll
        for (int p = 0; p < 4; ++p) {
            int pt = p * 16 + n;
            short4v hv;
#pragma unroll
            for (int r = 0; r < 4; ++r)
                hv[r] = f2bf(fmaxf(accF[p][r] + b0s[chb + r], 0.f));
            *(short4v*)&h[pt * HS + chb] = hv;
        }
    }
    __syncthreads();

    // phase 2: accS += h @ w1
    for (int ks = 0; ks < 4; ++ks) {
        int ko = ks * 32 + quad * 8;
        short8 a1 = *(const short8*)(Wt1r + (ch0 + n) * 128 + ko);
#pragma unroll
        for (int p = 0; p < 4; ++p) {
            short8 bh = *(const short8*)&h[(p * 16 + n) * HS + ko];
            accS[p] = __builtin_amdgcn_mfma_f32_16x16x32_bf16(a1, bh, accS[p], 0, 0, 0);
        }
    }
    __syncthreads();   // h reads done; reuse h for the output tile

    // epilogue stage 1: accS + b1 -> LDS (bf16, h layout)
    {
        int chb = ch0 + quad * 4;
#pragma unroll
        for (int p = 0; p < 4; ++p) {
            int pt = p * 16 + n;
            short4v o;
#pragma unroll
            for (int r = 0; r < 4; ++r)
                o[r] = f2bf(accS[p][r] + b1s[chb + r]);
            *(short4v*)&h[pt * HS + chb] = o;
        }
    }
    __syncthreads();

    // epilogue stage 2: coalesced store — 1KB contiguous per wave
    int pr = tid >> 4, l8 = (tid & 15) * 8;   // 32 rows per iteration
#pragma unroll
    for (int it = 0; it < 2; ++it) {
        int p = it * 32 + pr;
        *(short8*)(net_out + (t0 + p) * HID + l8) = *(const short8*)&h[p * HS + l8];
    }
}

// ---------- block 0: stage x = pts@Wp+bp (point-parallel), then resnet ----------
// grid (8, 469) x 512: batch = blockIdx.x (XCD affinity)
__global__ __launch_bounds__(512, 4) void k_mblock0(
    const float* __restrict__ pts, const float* __restrict__ Wp, const float* __restrict__ bp,
    const short* __restrict__ Wt0, const short* __restrict__ Wts, const short* __restrict__ Wt1,
    const float* __restrict__ b0, const float* __restrict__ b1, short* __restrict__ net)
{
    __shared__ short xs[PB * XS];
    __shared__ float b0s[HID], b1s[HID];
    int tid = threadIdx.x;
    int b  = blockIdx.x;
    int r0 = blockIdx.y * PB;
    if (tid < 128) { b0s[tid] = b0[tid]; b1s[tid] = b1[tid]; }

    // point-parallel staging: 8 threads per point, 32 cols each, b128 LDS writes
    int pt = tid >> 3;              // 0..63
    int sub = tid & 7;              // 32-col group
    int tt = r0 + pt; if (tt > TPTS - 1) tt = TPTS - 1;
    const float* pp = pts + (b * TPTS + tt) * 3;
    float px = pp[0], py = pp[1], pz = pp[2];
#pragma unroll
    for (int c8 = 0; c8 < 4; ++c8) {
        int col0 = sub * 32 + c8 * 8;
        short8 v8;
#pragma unroll
        for (int r = 0; r < 8; ++r) {
            int col = col0 + r;
            float v = fmaf(pz, Wp[512 + col], fmaf(py, Wp[256 + col], fmaf(px, Wp[col], bp[col])));
            v8[r] = f2bf(v);
        }
        *(short8*)&xs[pt * XS + col0] = v8;
    }
    __syncthreads();
    resnet_body(xs, b0s, b1s, Wt0, Wts, Wt1, net, b * NPR + r0);
}

// ---------- blocks 1..4: stage x = [net | pooled], then resnet ----------
// grid (8, 469) x 512: batch = blockIdx.x (XCD affinity — seg slice per batch fits one XCD L2)
__global__ __launch_bounds__(512, 4) void k_mblock(
    const short* __restrict__ net_in, const short* __restrict__ seg,
    const int* __restrict__ i0, const int* __restrict__ i1, const int* __restrict__ i2,
    const short* __restrict__ Wt0, const short* __restrict__ Wts, const short* __restrict__ Wt1,
    const float* __restrict__ b0, const float* __restrict__ b1, short* __restrict__ net_out)
{
    __shared__ short xs[PB * XS];
    __shared__ float b0s[HID], b1s[HID];
    int tid = threadIdx.x;
    int b  = blockIdx.x;
    int r0 = blockIdx.y * PB;
    if (tid < 128) { b0s[tid] = b0[tid]; b1s[tid] = b1[tid]; }

    int pr = tid >> 4;          // 32 rows per iteration
    int l8 = (tid & 15) * 8;    // short offset of 16B chunk
    // prefetch all indices first, then issue all gathers (ILP)
    int a0[2], a1[2], a2[2];
#pragma unroll
    for (int it = 0; it < 2; ++it) {
        int tt = r0 + it * 32 + pr;
        int ttc = tt > TPTS - 1 ? TPTS - 1 : tt;
        int ib = b * TPTS + ttc;
        a0[it] = i0[ib]; a1[it] = i1[ib]; a2[it] = i2[ib];
    }
#pragma unroll
    for (int it = 0; it < 2; ++it) {
        int p = it * 32 + pr;
        int tt = r0 + p;
        // raw net copy (already bf16); wave reads a contiguous 1KB block
        *(short8*)&xs[p * XS + l8] = *(const short8*)(net_in + (b * NPR + tt) * HID + l8);
        // pooled = sum of 3 plane maxima
        short8 s0 = *(const short8*)(seg + ((0 * BATCH + b) * R2 + a0[it]) * HID + l8);
        short8 s1 = *(const short8*)(seg + ((1 * BATCH + b) * R2 + a1[it]) * HID + l8);
        short8 s2 = *(const short8*)(seg + ((2 * BATCH + b) * R2 + a2[it]) * HID + l8);
        short8 pv;
#pragma unroll
        for (int r = 0; r < 8; ++r)
            pv[r] = f2bf(bf2f((unsigned short)s0[r]) + bf2f((unsigned short)s1[r]) + bf2f((unsigned short)s2[r]));
        *(short8*)&xs[p * XS + 128 + l8] = pv;
    }
    __syncthreads();
    resnet_body(xs, b0s, b1s, Wt0, Wts, Wt1, net_out, b * NPR + r0);
}

// ---------- out = (means @ Wc + bc)^T per plane-batch, empty bins -> 0 ----------
// grid (8, 192): batch = blockIdx.x, plane/bin-tile from blockIdx.y
__global__ __launch_bounds__(256) void k_gemmout(
    const short* __restrict__ meanb, const short* __restrict__ Wtc, const float* __restrict__ bc,
    const int* __restrict__ starts, float* __restrict__ out)
{
    __shared__ short bs[64 * HS];      // means bf16 [bin][k]
    __shared__ float tile[128 * 66];   // output f32 [ch][bin]
    __shared__ float bcs[HID];
    __shared__ int   flg[64];
    int tid = threadIdx.x;
    int b = blockIdx.x;
    int plane = blockIdx.y >> 6;
    int pb = plane * BATCH + b;
    int bin0 = (blockIdx.y & 63) * 64;

    if (tid < 128) bcs[tid] = bc[tid];
    if (tid < 64)  flg[tid] = (starts[pb * 4097 + bin0 + tid + 1] > starts[pb * 4097 + bin0 + tid]);
    for (int c8 = tid; c8 < 1024; c8 += 256) {
        int p = c8 >> 4, l = (c8 & 15) * 8;
        *(short8*)&bs[p * HS + l] = *(const short8*)(meanb + (pb * R2 + bin0 + p) * HID + l);
    }
    __syncthreads();

    int lane = tid & 63, wave = tid >> 6;
    int n = lane & 15, quad = lane >> 4;
    int ch0 = wave * 32;
    f32x4 acc[2][4] = {};
    for (int ks = 0; ks < 4; ++ks) {
        int ko = ks * 32 + quad * 8;
        short8 a[2];
#pragma unroll
        for (int c = 0; c < 2; ++c)
            a[c] = *(const short8*)(Wtc + (ch0 + c * 16 + n) * 128 + ko);
#pragma unroll
        for (int p = 0; p < 4; ++p) {
            short8 bh = *(const short8*)&bs[(p * 16 + n) * HS + ko];
#pragma unroll
            for (int c = 0; c < 2; ++c)
                acc[c][p] = __builtin_amdgcn_mfma_f32_16x16x32_bf16(a[c], bh, acc[c][p], 0, 0, 0);
        }
    }
#pragma unroll
    for (int c = 0; c < 2; ++c) {
        int chb = ch0 + c * 16 + quad * 4;
#pragma unroll
        for (int p = 0; p < 4; ++p) {
            int bin = p * 16 + n;
#pragma unroll
            for (int r = 0; r < 4; ++r)
                tile[(chb + r) * 66 + bin] = acc[c][p][r] + bcs[chb + r];
        }
    }
    __syncthreads();

    for (int c4 = tid; c4 < 2048; c4 += 256) {
        int ch = c4 >> 4, b4 = (c4 & 15) * 4;
        float4 o;
        o.x = flg[b4 + 0] ? tile[ch * 66 + b4 + 0] : 0.f;
        o.y = flg[b4 + 1] ? tile[ch * 66 + b4 + 1] : 0.f;
        o.z = flg[b4 + 2] ? tile[ch * 66 + b4 + 2] : 0.f;
        o.w = flg[b4 + 3] ? tile[ch * 66 + b4 + 3] : 0.f;
        *(float4*)(out + (pb * 128 + ch) * R2 + bin0 + b4) = o;
    }
}

extern "C" void kernel_launch(void* const* d_in, const int* in_sizes, int n_in,
                              void* d_out, int out_size, void* d_ws, size_t ws_size,
                              hipStream_t stream) {
    const float* pts  = (const float*)d_in[0];
    const int*   ixz  = (const int*)d_in[1];
    const int*   ixy  = (const int*)d_in[2];
    const int*   iyz  = (const int*)d_in[3];
    const float* Wp   = (const float*)d_in[4];
    const float* bp   = (const float*)d_in[5];
    const float* fc0w = (const float*)d_in[6];
    const float* fc0b = (const float*)d_in[7];
    const float* fc1w = (const float*)d_in[8];
    const float* fc1b = (const float*)d_in[9];
    const float* scw  = (const float*)d_in[10];
    const float* Wc   = (const float*)d_in[11];
    const float* bc   = (const float*)d_in[12];
    float* out = (float*)d_out;

    short* Wt0 = (short*)d_ws;             // 163840
    short* Wts = Wt0 + 163840;             // 163840
    short* Wt1 = Wts + 163840;             // 81920
    short* Wtc = Wt1 + 81920;              // 16384   (total 425984 shorts)
    short* net  = Wtc + 16384;             // 8*30016*128 shorts, bf16 (batch-padded)
    short* segb = net + 30736384;          // 12,582,912 shorts, bf16 (pool max / means)
    int* hist   = (int*)(segb + 12582912); // 98304 (doubles as cursor)
    int* starts = hist + 98304;            // 24*4097
    unsigned short* order = (unsigned short*)(starts + 98328); // 720000

    k_prep<<<dim3(640), 256, 0, stream>>>(fc0w, fc1w, scw, Wc, Wt0, Wts, Wt1, Wtc);
    k_fill4<<<dim3(96), 256, 0, stream>>>((float4*)hist, 0.f, 98304 / 4);
    k_hist<<<dim3((NPTS + 255) / 256), 256, 0, stream>>>(ixz, ixy, iyz, hist);
    k_scan<<<dim3(24), 256, 0, stream>>>(hist, starts, hist);
    k_scatter<<<dim3((NPTS + 255) / 256), 256, 0, stream>>>(ixz, ixy, iyz, hist, order);

    k_mblock0<<<dim3(8, NPR / PB), 512, 0, stream>>>(pts, Wp, bp, Wt0, Wts, Wt1, fc0b, fc1b, net);

    for (int r = 1; r < 5; ++r) {
        k_poolmax<<<dim3(8, 3 * R2 / 4), 256, 0, stream>>>(net, starts, order, segb);
        k_mblock<<<dim3(8, NPR / PB), 512, 0, stream>>>(
            net, segb, ixz, ixy, iyz,
            Wt0 + r * 32768, Wts + r * 32768, Wt1 + r * 16384,
            fc0b + r * 128, fc1b + r * 128, net);
    }

    // segment_mean(net@Wc+bc) == segment_mean(net)@Wc+bc  (bin means, then tiny GEMM)
    k_poolmean<<<dim3(8, 3 * R2 / 4), 256, 0, stream>>>(net, starts, order, segb);
    k_gemmout<<<dim3(8, 3 * 64), 256, 0, stream>>>(segb, Wtc, bc, starts, out);
}

// Round 9
// 933.299 us; speedup vs baseline: 1.1698x; 1.1698x over previous
//
#include <hip/hip_runtime.h>
#include <float.h>

#define BATCH 8
#define TPTS 30000
#define NPR 30016             // padded rows per batch (469 * 64)
#define HID 128
#define R2 4096
#define NPTS (BATCH * TPTS)   // 240000
#define PB 64                 // points per block
#define XS 264                // xs row stride in bf16 elems (256 + 8 pad)
#define HS 136                // h row stride (128 + 8 pad)

typedef __attribute__((ext_vector_type(8))) short short8;
typedef __attribute__((ext_vector_type(4))) short short4v;
typedef __attribute__((ext_vector_type(4))) float f32x4;

__device__ __forceinline__ short f2bf(float f) {
    unsigned u = __float_as_uint(f);
    u += 0x7fff + ((u >> 16) & 1);   // RNE
    return (short)(u >> 16);
}
__device__ __forceinline__ float bf2f(unsigned short u) {
    return __uint_as_float(((unsigned)u) << 16);
}
// packed relu on two bf16 in one dword: negative -> sign-only (-0.0, harmless as matmul input)
__device__ __forceinline__ unsigned relu2(unsigned u) {
    unsigned sm = u & 0x80008000u;
    unsigned d  = sm - (sm >> 15);
    return u & ~d;
}
__device__ __forceinline__ short8 relu8(short8 v) {
    union { short8 s; unsigned u[4]; } a;
    a.s = v;
#pragma unroll
    for (int i = 0; i < 4; ++i) a.u[i] = relu2(a.u[i]);
    return a.s;
}

__global__ void k_fill4(float4* p, float v, int n4) {
    int i = blockIdx.x * blockDim.x + threadIdx.x;
    if (i < n4) p[i] = make_float4(v, v, v, v);
}

// ---------- weight prep: f32 [k][ch] -> bf16 transposed [ch][k] ----------
__global__ __launch_bounds__(256) void k_prep(
    const float* __restrict__ fc0w, const float* __restrict__ fc1w, const float* __restrict__ scw,
    const float* __restrict__ fccw,
    short* __restrict__ Wt0, short* __restrict__ Wts, short* __restrict__ Wt1,
    short* __restrict__ Wtc)
{
    int i = blockIdx.x * 256 + threadIdx.x;
    if (i < 5 * 128 * 256) {
        int r = i >> 15;
        int c = (i >> 8) & 127;
        int k = i & 255;
        Wt0[i] = f2bf(fc0w[(r * 256 + k) * 128 + c]);
        Wts[i] = f2bf(scw [(r * 256 + k) * 128 + c]);
    }
    if (i < 5 * 128 * 128) {
        int r = i >> 14;
        int c = (i >> 7) & 127;
        int k = i & 127;
        Wt1[i] = f2bf(fc1w[(r * 128 + k) * 128 + c]);
    }
    if (i < 128 * 128) {
        int c = (i >> 7) & 127;
        int k = i & 127;
        Wtc[i] = f2bf(fccw[k * 128 + c]);
    }
}

// ---------- counting sort of points by bin (per plane, per batch) ----------
__global__ void k_hist(const int* __restrict__ i0, const int* __restrict__ i1,
                       const int* __restrict__ i2, int* __restrict__ hist)
{
    int t = blockIdx.x * 256 + threadIdx.x;
    if (t >= NPTS) return;
    int b = t / TPTS;
    atomicAdd(&hist[(0 * BATCH + b) * R2 + i0[t]], 1);
    atomicAdd(&hist[(1 * BATCH + b) * R2 + i1[t]], 1);
    atomicAdd(&hist[(2 * BATCH + b) * R2 + i2[t]], 1);
}

__global__ __launch_bounds__(256) void k_scan(const int* __restrict__ hist,
                                              int* __restrict__ starts, int* __restrict__ cursor)
{
    int pb = blockIdx.x;                 // 0..23
    const int* h = hist + pb * R2;
    int tid = threadIdx.x;
    __shared__ int part[257];
    int loc[16]; int s = 0;
    int base = tid * 16;
#pragma unroll
    for (int q = 0; q < 16; ++q) { loc[q] = s; s += h[base + q]; }
    part[tid + 1] = s;
    __syncthreads();
    if (tid == 0) {
        part[0] = 0;
        for (int i = 1; i <= 256; ++i) part[i] += part[i - 1];
    }
    __syncthreads();
    int off = part[tid];
#pragma unroll
    for (int q = 0; q < 16; ++q) {
        int v = off + loc[q];
        starts[pb * 4097 + base + q] = v;
        cursor[pb * R2 + base + q] = v;
    }
    if (tid == 255) starts[pb * 4097 + 4096] = part[256];
}

__global__ void k_scatter(const int* __restrict__ i0, const int* __restrict__ i1,
                          const int* __restrict__ i2, int* __restrict__ cursor,
                          unsigned short* __restrict__ order)
{
    int t = blockIdx.x * 256 + threadIdx.x;
    if (t >= NPTS) return;
    int b = t / TPTS;
    int tt = t - b * TPTS;
    int s0 = atomicAdd(&cursor[(0 * BATCH + b) * R2 + i0[t]], 1);
    order[(0 * BATCH + b) * TPTS + s0] = (unsigned short)tt;
    int s1 = atomicAdd(&cursor[(1 * BATCH + b) * R2 + i1[t]], 1);
    order[(1 * BATCH + b) * TPTS + s1] = (unsigned short)tt;
    int s2 = atomicAdd(&cursor[(2 * BATCH + b) * R2 + i2[t]], 1);
    order[(2 * BATCH + b) * TPTS + s2] = (unsigned short)tt;
}

// ---------- gather-based pool max over bf16 net: one wave per bin, 4-deep pipelined ----------
// grid (8, 3072): batch = blockIdx.x (XCD affinity), plane/bin from blockIdx.y
__global__ __launch_bounds__(256) void k_poolmax(
    const short* __restrict__ net, const int* __restrict__ starts,
    const unsigned short* __restrict__ order, short* __restrict__ seg)
{
    int b = blockIdx.x;
    int plane = blockIdx.y >> 10;
    int bin = (blockIdx.y & 1023) * 4 + (threadIdx.x >> 6);
    int pb = plane * BATCH + b;
    int lane = threadIdx.x & 63;
    int s = starts[pb * 4097 + bin], e = starts[pb * 4097 + bin + 1];
    if (s == e) return;                       // empty bins never gathered
    const unsigned short* ord = order + pb * TPTS;
    const short* nb = net + (size_t)b * NPR * HID + lane * 2;
    float vx = -FLT_MAX, vy = -FLT_MAX;
    int i = s;
    for (; i + 4 <= e; i += 4) {              // 4 loads in flight per iter
        unsigned u0 = *(const unsigned*)(nb + (int)ord[i + 0] * HID);
        unsigned u1 = *(const unsigned*)(nb + (int)ord[i + 1] * HID);
        unsigned u2 = *(const unsigned*)(nb + (int)ord[i + 2] * HID);
        unsigned u3 = *(const unsigned*)(nb + (int)ord[i + 3] * HID);
        vx = fmaxf(fmaxf(vx, bf2f((unsigned short)(u0 & 0xFFFF))),
                   fmaxf(bf2f((unsigned short)(u1 & 0xFFFF)),
                         fmaxf(bf2f((unsigned short)(u2 & 0xFFFF)), bf2f((unsigned short)(u3 & 0xFFFF)))));
        vy = fmaxf(fmaxf(vy, bf2f((unsigned short)(u0 >> 16))),
                   fmaxf(bf2f((unsigned short)(u1 >> 16)),
                         fmaxf(bf2f((unsigned short)(u2 >> 16)), bf2f((unsigned short)(u3 >> 16)))));
    }
    for (; i < e; ++i) {
        unsigned u = *(const unsigned*)(nb + (int)ord[i] * HID);
        vx = fmaxf(vx, bf2f((unsigned short)(u & 0xFFFF)));
        vy = fmaxf(vy, bf2f((unsigned short)(u >> 16)));
    }
    unsigned o = ((unsigned short)f2bf(vx)) | (((unsigned)(unsigned short)f2bf(vy)) << 16);
    *(unsigned*)(seg + (pb * R2 + bin) * HID + lane * 2) = o;
}

// ---------- gather-based pool mean over bf16 net -> bf16 means [pb][bin][128] ----------
__global__ __launch_bounds__(256) void k_poolmean(
    const short* __restrict__ net, const int* __restrict__ starts,
    const unsigned short* __restrict__ order, short* __restrict__ meanb)
{
    int b = blockIdx.x;
    int plane = blockIdx.y >> 10;
    int bin = (blockIdx.y & 1023) * 4 + (threadIdx.x >> 6);
    int pb = plane * BATCH + b;
    int lane = threadIdx.x & 63;
    int s = starts[pb * 4097 + bin], e = starts[pb * 4097 + bin + 1];
    const unsigned short* ord = order + pb * TPTS;
    const short* nb = net + (size_t)b * NPR * HID + lane * 2;
    float vx = 0.f, vy = 0.f;
    int i = s;
    for (; i + 4 <= e; i += 4) {
        unsigned u0 = *(const unsigned*)(nb + (int)ord[i + 0] * HID);
        unsigned u1 = *(const unsigned*)(nb + (int)ord[i + 1] * HID);
        unsigned u2 = *(const unsigned*)(nb + (int)ord[i + 2] * HID);
        unsigned u3 = *(const unsigned*)(nb + (int)ord[i + 3] * HID);
        vx += (bf2f((unsigned short)(u0 & 0xFFFF)) + bf2f((unsigned short)(u1 & 0xFFFF)))
            + (bf2f((unsigned short)(u2 & 0xFFFF)) + bf2f((unsigned short)(u3 & 0xFFFF)));
        vy += (bf2f((unsigned short)(u0 >> 16)) + bf2f((unsigned short)(u1 >> 16)))
            + (bf2f((unsigned short)(u2 >> 16)) + bf2f((unsigned short)(u3 >> 16)));
    }
    for (; i < e; ++i) {
        unsigned u = *(const unsigned*)(nb + (int)ord[i] * HID);
        vx += bf2f((unsigned short)(u & 0xFFFF));
        vy += bf2f((unsigned short)(u >> 16));
    }
    float inv = 1.f / fmaxf((float)(e - s), 1.f);
    unsigned o = ((unsigned short)f2bf(vx * inv)) | (((unsigned)(unsigned short)f2bf(vy * inv)) << 16);
    *(unsigned*)(meanb + (pb * R2 + bin) * HID + lane * 2) = o;   // empty bins -> 0
}

// ---------- resnet body: 4 waves x 32ch, merged S+F phase, direct-store epilogue ----------
// 3 barriers. Direct 8B frag stores coalesce in batch-local L2 (XCD swizzle), WRITE stays ~ideal.
__device__ __forceinline__ void resnet_body(
    short* xs, const float* b0s, const float* b1s,
    const short* __restrict__ Wt0r, const short* __restrict__ Wtsr,
    const short* __restrict__ Wt1r, short* __restrict__ net_out, int t0)
{
    int tid = threadIdx.x;
    int lane = tid & 63;
    int wave = tid >> 6;
    int n    = lane & 15;
    int quad = lane >> 4;
    int ch0  = wave * 32;

    // merged phase: accS = x @ wsc ; accF = relu(x) @ w0   (one B-load, 4 MFMAs)
    f32x4 accS[2][4] = {};
    f32x4 accF[2][4] = {};
    for (int ks = 0; ks < 8; ++ks) {
        int ko = ks * 32 + quad * 8;
        short8 aS[2], aF[2];
#pragma unroll
        for (int c = 0; c < 2; ++c) {
            int row = ch0 + c * 16 + n;
            aS[c] = *(const short8*)(Wtsr + row * 256 + ko);
            aF[c] = *(const short8*)(Wt0r + row * 256 + ko);
        }
#pragma unroll
        for (int p = 0; p < 4; ++p) {
            short8 bX = *(const short8*)(xs + (p * 16 + n) * XS + ko);
            short8 bR = relu8(bX);
#pragma unroll
            for (int c = 0; c < 2; ++c) {
                accS[c][p] = __builtin_amdgcn_mfma_f32_16x16x32_bf16(aS[c], bX, accS[c][p], 0, 0, 0);
                accF[c][p] = __builtin_amdgcn_mfma_f32_16x16x32_bf16(aF[c], bR, accF[c][p], 0, 0, 0);
            }
        }
    }
    __syncthreads();   // all xs reads done; safe to alias h

    short* h = xs;
#pragma unroll
    for (int c = 0; c < 2; ++c) {
        int chb = ch0 + c * 16 + quad * 4;
#pragma unroll
        for (int p = 0; p < 4; ++p) {
            int pt = p * 16 + n;
            short4v hv;
#pragma unroll
            for (int r = 0; r < 4; ++r)
                hv[r] = f2bf(fmaxf(accF[c][p][r] + b0s[chb + r], 0.f));
            *(short4v*)&h[pt * HS + chb] = hv;
        }
    }
    __syncthreads();

    // phase 2: accS += h @ w1
    for (int ks = 0; ks < 4; ++ks) {
        int ko = ks * 32 + quad * 8;
        short8 a1[2];
#pragma unroll
        for (int c = 0; c < 2; ++c)
            a1[c] = *(const short8*)(Wt1r + (ch0 + c * 16 + n) * 128 + ko);
#pragma unroll
        for (int p = 0; p < 4; ++p) {
            short8 bh = *(const short8*)&h[(p * 16 + n) * HS + ko];
#pragma unroll
            for (int c = 0; c < 2; ++c)
                accS[c][p] = __builtin_amdgcn_mfma_f32_16x16x32_bf16(a1[c], bh, accS[c][p], 0, 0, 0);
        }
    }

    // epilogue: direct 8B frag stores (batch-local L2 coalesces; no barrier needed)
#pragma unroll
    for (int c = 0; c < 2; ++c) {
        int chb = ch0 + c * 16 + quad * 4;
#pragma unroll
        for (int p = 0; p < 4; ++p) {
            int pt = p * 16 + n;
            short4v o;
#pragma unroll
            for (int r = 0; r < 4; ++r)
                o[r] = f2bf(accS[c][p][r] + b1s[chb + r]);
            *(short4v*)(net_out + (t0 + pt) * HID + chb) = o;
        }
    }
}

// ---------- block 0: stage x = pts@Wp+bp (point-parallel, b128 writes), then resnet ----------
// grid (8, 469) x 256: batch = blockIdx.x (XCD affinity)
__global__ __launch_bounds__(256, 4) void k_mblock0(
    const float* __restrict__ pts, const float* __restrict__ Wp, const float* __restrict__ bp,
    const short* __restrict__ Wt0, const short* __restrict__ Wts, const short* __restrict__ Wt1,
    const float* __restrict__ b0, const float* __restrict__ b1, short* __restrict__ net)
{
    __shared__ short xs[PB * XS];
    __shared__ float b0s[HID], b1s[HID];
    int tid = threadIdx.x;
    int b  = blockIdx.x;
    int r0 = blockIdx.y * PB;
    if (tid < 128) { b0s[tid] = b0[tid]; b1s[tid] = b1[tid]; }

    // point-parallel staging: 4 threads per point, 64 cols each, b128 LDS writes
    int pt = tid >> 2;              // 0..63
    int sub = tid & 3;              // 64-col group
    int tt = r0 + pt; if (tt > TPTS - 1) tt = TPTS - 1;   // tail rows: duplicate last point
    const float* pp = pts + (b * TPTS + tt) * 3;
    float px = pp[0], py = pp[1], pz = pp[2];
#pragma unroll
    for (int c8 = 0; c8 < 8; ++c8) {
        int col0 = sub * 64 + c8 * 8;
        short8 v8;
#pragma unroll
        for (int r = 0; r < 8; ++r) {
            int col = col0 + r;
            float v = fmaf(pz, Wp[512 + col], fmaf(py, Wp[256 + col], fmaf(px, Wp[col], bp[col])));
            v8[r] = f2bf(v);
        }
        *(short8*)&xs[pt * XS + col0] = v8;
    }
    __syncthreads();
    resnet_body(xs, b0s, b1s, Wt0, Wts, Wt1, net, b * NPR + r0);
}

// ---------- blocks 1..4: stage x = [net | pooled], then resnet ----------
// grid (8, 469) x 256: batch = blockIdx.x (XCD affinity — seg slice per batch fits one XCD L2)
__global__ __launch_bounds__(256, 4) void k_mblock(
    const short* __restrict__ net_in, const short* __restrict__ seg,
    const int* __restrict__ i0, const int* __restrict__ i1, const int* __restrict__ i2,
    const short* __restrict__ Wt0, const short* __restrict__ Wts, const short* __restrict__ Wt1,
    const float* __restrict__ b0, const float* __restrict__ b1, short* __restrict__ net_out)
{
    __shared__ short xs[PB * XS];
    __shared__ float b0s[HID], b1s[HID];
    int tid = threadIdx.x;
    int b  = blockIdx.x;
    int r0 = blockIdx.y * PB;
    if (tid < 128) { b0s[tid] = b0[tid]; b1s[tid] = b1[tid]; }

    int pr = tid >> 4;          // row within group of 16 (16 rows per iter)
    int l8 = (tid & 15) * 8;    // short offset of 16B chunk: 0..120
    // prefetch all indices first, then issue all gathers (ILP)
    int a0[4], a1[4], a2[4];
#pragma unroll
    for (int it = 0; it < 4; ++it) {
        int tt = r0 + it * 16 + pr;
        int ttc = tt > TPTS - 1 ? TPTS - 1 : tt;
        int ib = b * TPTS + ttc;
        a0[it] = i0[ib]; a1[it] = i1[ib]; a2[it] = i2[ib];
    }
#pragma unroll
    for (int it = 0; it < 4; ++it) {
        int p = it * 16 + pr;
        int tt = r0 + p;
        // raw net copy (already bf16); wave reads a contiguous 1KB block
        *(short8*)&xs[p * XS + l8] = *(const short8*)(net_in + (b * NPR + tt) * HID + l8);
        // pooled = sum of 3 plane maxima
        short8 s0 = *(const short8*)(seg + ((0 * BATCH + b) * R2 + a0[it]) * HID + l8);
        short8 s1 = *(const short8*)(seg + ((1 * BATCH + b) * R2 + a1[it]) * HID + l8);
        short8 s2 = *(const short8*)(seg + ((2 * BATCH + b) * R2 + a2[it]) * HID + l8);
        short8 pv;
#pragma unroll
        for (int r = 0; r < 8; ++r)
            pv[r] = f2bf(bf2f((unsigned short)s0[r]) + bf2f((unsigned short)s1[r]) + bf2f((unsigned short)s2[r]));
        *(short8*)&xs[p * XS + 128 + l8] = pv;
    }
    __syncthreads();
    resnet_body(xs, b0s, b1s, Wt0, Wts, Wt1, net_out, b * NPR + r0);
}

// ---------- out = (means @ Wc + bc)^T per plane-batch, empty bins -> 0 ----------
// grid (8, 192): batch = blockIdx.x, plane/bin-tile from blockIdx.y
__global__ __launch_bounds__(256) void k_gemmout(
    const short* __restrict__ meanb, const short* __restrict__ Wtc, const float* __restrict__ bc,
    const int* __restrict__ starts, float* __restrict__ out)
{
    __shared__ short bs[64 * HS];      // means bf16 [bin][k]
    __shared__ float tile[128 * 66];   // output f32 [ch][bin]
    __shared__ float bcs[HID];
    __shared__ int   flg[64];
    int tid = threadIdx.x;
    int b = blockIdx.x;
    int plane = blockIdx.y >> 6;
    int pb = plane * BATCH + b;
    int bin0 = (blockIdx.y & 63) * 64;

    if (tid < 128) bcs[tid] = bc[tid];
    if (tid < 64)  flg[tid] = (starts[pb * 4097 + bin0 + tid + 1] > starts[pb * 4097 + bin0 + tid]);
    for (int c8 = tid; c8 < 1024; c8 += 256) {
        int p = c8 >> 4, l = (c8 & 15) * 8;
        *(short8*)&bs[p * HS + l] = *(const short8*)(meanb + (pb * R2 + bin0 + p) * HID + l);
    }
    __syncthreads();

    int lane = tid & 63, wave = tid >> 6;
    int n = lane & 15, quad = lane >> 4;
    int ch0 = wave * 32;
    f32x4 acc[2][4] = {};
    for (int ks = 0; ks < 4; ++ks) {
        int ko = ks * 32 + quad * 8;
        short8 a[2];
#pragma unroll
        for (int c = 0; c < 2; ++c)
            a[c] = *(const short8*)(Wtc + (ch0 + c * 16 + n) * 128 + ko);
#pragma unroll
        for (int p = 0; p < 4; ++p) {
            short8 bh = *(const short8*)&bs[(p * 16 + n) * HS + ko];
#pragma unroll
            for (int c = 0; c < 2; ++c)
                acc[c][p] = __builtin_amdgcn_mfma_f32_16x16x32_bf16(a[c], bh, acc[c][p], 0, 0, 0);
        }
    }
#pragma unroll
    for (int c = 0; c < 2; ++c) {
        int chb = ch0 + c * 16 + quad * 4;
#pragma unroll
        for (int p = 0; p < 4; ++p) {
            int bin = p * 16 + n;
#pragma unroll
            for (int r = 0; r < 4; ++r)
                tile[(chb + r) * 66 + bin] = acc[c][p][r] + bcs[chb + r];
        }
    }
    __syncthreads();

    for (int c4 = tid; c4 < 2048; c4 += 256) {
        int ch = c4 >> 4, b4 = (c4 & 15) * 4;
        float4 o;
        o.x = flg[b4 + 0] ? tile[ch * 66 + b4 + 0] : 0.f;
        o.y = flg[b4 + 1] ? tile[ch * 66 + b4 + 1] : 0.f;
        o.z = flg[b4 + 2] ? tile[ch * 66 + b4 + 2] : 0.f;
        o.w = flg[b4 + 3] ? tile[ch * 66 + b4 + 3] : 0.f;
        *(float4*)(out + (pb * 128 + ch) * R2 + bin0 + b4) = o;
    }
}

extern "C" void kernel_launch(void* const* d_in, const int* in_sizes, int n_in,
                              void* d_out, int out_size, void* d_ws, size_t ws_size,
                              hipStream_t stream) {
    const float* pts  = (const float*)d_in[0];
    const int*   ixz  = (const int*)d_in[1];
    const int*   ixy  = (const int*)d_in[2];
    const int*   iyz  = (const int*)d_in[3];
    const float* Wp   = (const float*)d_in[4];
    const float* bp   = (const float*)d_in[5];
    const float* fc0w = (const float*)d_in[6];
    const float* fc0b = (const float*)d_in[7];
    const float* fc1w = (const float*)d_in[8];
    const float* fc1b = (const float*)d_in[9];
    const float* scw  = (const float*)d_in[10];
    const float* Wc   = (const float*)d_in[11];
    const float* bc   = (const float*)d_in[12];
    float* out = (float*)d_out;

    short* Wt0 = (short*)d_ws;             // 163840
    short* Wts = Wt0 + 163840;             // 163840
    short* Wt1 = Wts + 163840;             // 81920
    short* Wtc = Wt1 + 81920;              // 16384   (total 425984 shorts)
    short* net  = Wtc + 16384;             // 8*30016*128 shorts, bf16 (batch-padded)
    short* segb = net + 30736384;          // 12,582,912 shorts, bf16 (pool max / means)
    int* hist   = (int*)(segb + 12582912); // 98304 (doubles as cursor)
    int* starts = hist + 98304;            // 24*4097
    unsigned short* order = (unsigned short*)(starts + 98328); // 720000

    k_prep<<<dim3(640), 256, 0, stream>>>(fc0w, fc1w, scw, Wc, Wt0, Wts, Wt1, Wtc);
    k_fill4<<<dim3(96), 256, 0, stream>>>((float4*)hist, 0.f, 98304 / 4);
    k_hist<<<dim3((NPTS + 255) / 256), 256, 0, stream>>>(ixz, ixy, iyz, hist);
    k_scan<<<dim3(24), 256, 0, stream>>>(hist, starts, hist);
    k_scatter<<<dim3((NPTS + 255) / 256), 256, 0, stream>>>(ixz, ixy, iyz, hist, order);

    k_mblock0<<<dim3(8, NPR / PB), 256, 0, stream>>>(pts, Wp, bp, Wt0, Wts, Wt1, fc0b, fc1b, net);

    for (int r = 1; r < 5; ++r) {
        k_poolmax<<<dim3(8, 3 * R2 / 4), 256, 0, stream>>>(net, starts, order, segb);
        k_mblock<<<dim3(8, NPR / PB), 256, 0, stream>>>(
            net, segb, ixz, ixy, iyz,
            Wt0 + r * 32768, Wts + r * 32768, Wt1 + r * 16384,
            fc0b + r * 128, fc1b + r * 128, net);
    }

    // segment_mean(net@Wc+bc) == segment_mean(net)@Wc+bc  (bin means, then tiny GEMM)
    k_poolmean<<<dim3(8, 3 * R2 / 4), 256, 0, stream>>>(net, starts, order, segb);
    k_gemmout<<<dim3(8, 3 * 64), 256, 0, stream>>>(segb, Wtc, bc, starts, out);
}

// Round 10
// 818.061 us; speedup vs baseline: 1.3346x; 1.1409x over previous
//
#include <hip/hip_runtime.h>
#include <float.h>

#define BATCH 8
#define TPTS 30000
#define NPR 30016             // padded rows per batch (469 * 64)
#define HID 128
#define R2 4096
#define NPTS (BATCH * TPTS)   // 240000
#define PB 64                 // points per block
#define XS 264                // xs row stride in bf16 elems (256 + 8 pad)
#define HS 136                // h row stride (128 + 8 pad)

typedef __attribute__((ext_vector_type(8))) short short8;
typedef __attribute__((ext_vector_type(4))) short short4v;
typedef __attribute__((ext_vector_type(4))) float f32x4;

__device__ __forceinline__ short f2bf(float f) {
    unsigned u = __float_as_uint(f);
    u += 0x7fff + ((u >> 16) & 1);   // RNE
    return (short)(u >> 16);
}
__device__ __forceinline__ float bf2f(unsigned short u) {
    return __uint_as_float(((unsigned)u) << 16);
}
// packed relu on two bf16 in one dword: negative -> sign-only (-0.0, harmless as matmul input)
__device__ __forceinline__ unsigned relu2(unsigned u) {
    unsigned sm = u & 0x80008000u;
    unsigned d  = sm - (sm >> 15);
    return u & ~d;
}
__device__ __forceinline__ short8 relu8(short8 v) {
    union { short8 s; unsigned u[4]; } a;
    a.s = v;
#pragma unroll
    for (int i = 0; i < 4; ++i) a.u[i] = relu2(a.u[i]);
    return a.s;
}

__global__ void k_fill4(float4* p, float v, int n4) {
    int i = blockIdx.x * blockDim.x + threadIdx.x;
    if (i < n4) p[i] = make_float4(v, v, v, v);
}

// ---------- weight prep: f32 [k][ch] -> bf16 transposed [ch][k] ----------
__global__ __launch_bounds__(256) void k_prep(
    const float* __restrict__ fc0w, const float* __restrict__ fc1w, const float* __restrict__ scw,
    const float* __restrict__ fccw,
    short* __restrict__ Wt0, short* __restrict__ Wts, short* __restrict__ Wt1,
    short* __restrict__ Wtc)
{
    int i = blockIdx.x * 256 + threadIdx.x;
    if (i < 5 * 128 * 256) {
        int r = i >> 15;
        int c = (i >> 8) & 127;
        int k = i & 255;
        Wt0[i] = f2bf(fc0w[(r * 256 + k) * 128 + c]);
        Wts[i] = f2bf(scw [(r * 256 + k) * 128 + c]);
    }
    if (i < 5 * 128 * 128) {
        int r = i >> 14;
        int c = (i >> 7) & 127;
        int k = i & 127;
        Wt1[i] = f2bf(fc1w[(r * 128 + k) * 128 + c]);
    }
    if (i < 128 * 128) {
        int c = (i >> 7) & 127;
        int k = i & 127;
        Wtc[i] = f2bf(fccw[k * 128 + c]);
    }
}

// ---------- counting sort of points by bin (per plane, per batch) ----------
__global__ void k_hist(const int* __restrict__ i0, const int* __restrict__ i1,
                       const int* __restrict__ i2, int* __restrict__ hist)
{
    int t = blockIdx.x * 256 + threadIdx.x;
    if (t >= NPTS) return;
    int b = t / TPTS;
    atomicAdd(&hist[(0 * BATCH + b) * R2 + i0[t]], 1);
    atomicAdd(&hist[(1 * BATCH + b) * R2 + i1[t]], 1);
    atomicAdd(&hist[(2 * BATCH + b) * R2 + i2[t]], 1);
}

__global__ __launch_bounds__(256) void k_scan(const int* __restrict__ hist,
                                              int* __restrict__ starts, int* __restrict__ cursor)
{
    int pb = blockIdx.x;                 // 0..23
    const int* h = hist + pb * R2;
    int tid = threadIdx.x;
    __shared__ int part[257];
    int loc[16]; int s = 0;
    int base = tid * 16;
#pragma unroll
    for (int q = 0; q < 16; ++q) { loc[q] = s; s += h[base + q]; }
    part[tid + 1] = s;
    __syncthreads();
    if (tid == 0) {
        part[0] = 0;
        for (int i = 1; i <= 256; ++i) part[i] += part[i - 1];
    }
    __syncthreads();
    int off = part[tid];
#pragma unroll
    for (int q = 0; q < 16; ++q) {
        int v = off + loc[q];
        starts[pb * 4097 + base + q] = v;
        cursor[pb * R2 + base + q] = v;
    }
    if (tid == 255) starts[pb * 4097 + 4096] = part[256];
}

__global__ void k_scatter(const int* __restrict__ i0, const int* __restrict__ i1,
                          const int* __restrict__ i2, int* __restrict__ cursor,
                          unsigned short* __restrict__ order)
{
    int t = blockIdx.x * 256 + threadIdx.x;
    if (t >= NPTS) return;
    int b = t / TPTS;
    int tt = t - b * TPTS;
    int s0 = atomicAdd(&cursor[(0 * BATCH + b) * R2 + i0[t]], 1);
    order[(0 * BATCH + b) * TPTS + s0] = (unsigned short)tt;
    int s1 = atomicAdd(&cursor[(1 * BATCH + b) * R2 + i1[t]], 1);
    order[(1 * BATCH + b) * TPTS + s1] = (unsigned short)tt;
    int s2 = atomicAdd(&cursor[(2 * BATCH + b) * R2 + i2[t]], 1);
    order[(2 * BATCH + b) * TPTS + s2] = (unsigned short)tt;
}

// ---------- gather-based pool max: clamped 4-unroll (no serial tail; dup-safe for max) ----------
// grid (8, 3072): batch = blockIdx.x (XCD affinity), plane/bin from blockIdx.y
__global__ __launch_bounds__(256) void k_poolmax(
    const short* __restrict__ net, const int* __restrict__ starts,
    const unsigned short* __restrict__ order, short* __restrict__ seg)
{
    int b = blockIdx.x;
    int plane = blockIdx.y >> 10;
    int bin = (blockIdx.y & 1023) * 4 + (threadIdx.x >> 6);
    int pb = plane * BATCH + b;
    int lane = threadIdx.x & 63;
    int s = starts[pb * 4097 + bin], e = starts[pb * 4097 + bin + 1];
    if (s == e) return;                       // empty bins never gathered
    const unsigned short* ord = order + pb * TPTS;
    const short* nb = net + (size_t)b * NPR * HID + lane * 2;
    float vx = -FLT_MAX, vy = -FLT_MAX;
    int last = e - 1;
    for (int i = s; i < e; i += 4) {          // indices clamped: duplicates harmless for max
        int j1 = i + 1 > last ? last : i + 1;
        int j2 = i + 2 > last ? last : i + 2;
        int j3 = i + 3 > last ? last : i + 3;
        unsigned u0 = *(const unsigned*)(nb + (int)ord[i]  * HID);
        unsigned u1 = *(const unsigned*)(nb + (int)ord[j1] * HID);
        unsigned u2 = *(const unsigned*)(nb + (int)ord[j2] * HID);
        unsigned u3 = *(const unsigned*)(nb + (int)ord[j3] * HID);
        vx = fmaxf(fmaxf(vx, bf2f((unsigned short)(u0 & 0xFFFF))),
                   fmaxf(bf2f((unsigned short)(u1 & 0xFFFF)),
                         fmaxf(bf2f((unsigned short)(u2 & 0xFFFF)), bf2f((unsigned short)(u3 & 0xFFFF)))));
        vy = fmaxf(fmaxf(vy, bf2f((unsigned short)(u0 >> 16))),
                   fmaxf(bf2f((unsigned short)(u1 >> 16)),
                         fmaxf(bf2f((unsigned short)(u2 >> 16)), bf2f((unsigned short)(u3 >> 16)))));
    }
    unsigned o = ((unsigned short)f2bf(vx)) | (((unsigned)(unsigned short)f2bf(vy)) << 16);
    *(unsigned*)(seg + (pb * R2 + bin) * HID + lane * 2) = o;
}

// ---------- gather-based pool mean: clamped 4-unroll, duplicates masked to 0 ----------
__global__ __launch_bounds__(256) void k_poolmean(
    const short* __restrict__ net, const int* __restrict__ starts,
    const unsigned short* __restrict__ order, short* __restrict__ meanb)
{
    int b = blockIdx.x;
    int plane = blockIdx.y >> 10;
    int bin = (blockIdx.y & 1023) * 4 + (threadIdx.x >> 6);
    int pb = plane * BATCH + b;
    int lane = threadIdx.x & 63;
    int s = starts[pb * 4097 + bin], e = starts[pb * 4097 + bin + 1];
    const unsigned short* ord = order + pb * TPTS;
    const short* nb = net + (size_t)b * NPR * HID + lane * 2;
    float vx = 0.f, vy = 0.f;
    int last = e - 1;
    for (int i = s; i < e; i += 4) {
        int j1 = i + 1 > last ? last : i + 1;
        int j2 = i + 2 > last ? last : i + 2;
        int j3 = i + 3 > last ? last : i + 3;
        unsigned u0 = *(const unsigned*)(nb + (int)ord[i]  * HID);
        unsigned u1 = *(const unsigned*)(nb + (int)ord[j1] * HID);
        unsigned u2 = *(const unsigned*)(nb + (int)ord[j2] * HID);
        unsigned u3 = *(const unsigned*)(nb + (int)ord[j3] * HID);
        float m1 = (i + 1 <= last) ? 1.f : 0.f;
        float m2 = (i + 2 <= last) ? 1.f : 0.f;
        float m3 = (i + 3 <= last) ? 1.f : 0.f;
        vx += bf2f((unsigned short)(u0 & 0xFFFF)) + m1 * bf2f((unsigned short)(u1 & 0xFFFF))
            + m2 * bf2f((unsigned short)(u2 & 0xFFFF)) + m3 * bf2f((unsigned short)(u3 & 0xFFFF));
        vy += bf2f((unsigned short)(u0 >> 16)) + m1 * bf2f((unsigned short)(u1 >> 16))
            + m2 * bf2f((unsigned short)(u2 >> 16)) + m3 * bf2f((unsigned short)(u3 >> 16));
    }
    float inv = 1.f / fmaxf((float)(e - s), 1.f);
    unsigned o = ((unsigned short)f2bf(vx * inv)) | (((unsigned)(unsigned short)f2bf(vy * inv)) << 16);
    *(unsigned*)(meanb + (pb * R2 + bin) * HID + lane * 2) = o;   // empty bins -> 0
}

// ---------- resnet body: 4 waves x 32ch, merged S+F phase, direct-store epilogue ----------
__device__ __forceinline__ void resnet_body(
    short* xs, const float* b0s, const float* b1s,
    const short* __restrict__ Wt0r, const short* __restrict__ Wtsr,
    const short* __restrict__ Wt1r, short* __restrict__ net_out, int t0)
{
    int tid = threadIdx.x;
    int lane = tid & 63;
    int wave = tid >> 6;
    int n    = lane & 15;
    int quad = lane >> 4;
    int ch0  = wave * 32;

    // merged phase: accS = x @ wsc ; accF = relu(x) @ w0   (one B-load, 4 MFMAs)
    f32x4 accS[2][4] = {};
    f32x4 accF[2][4] = {};
    for (int ks = 0; ks < 8; ++ks) {
        int ko = ks * 32 + quad * 8;
        short8 aS[2], aF[2];
#pragma unroll
        for (int c = 0; c < 2; ++c) {
            int row = ch0 + c * 16 + n;
            aS[c] = *(const short8*)(Wtsr + row * 256 + ko);
            aF[c] = *(const short8*)(Wt0r + row * 256 + ko);
        }
#pragma unroll
        for (int p = 0; p < 4; ++p) {
            short8 bX = *(const short8*)(xs + (p * 16 + n) * XS + ko);
            short8 bR = relu8(bX);
#pragma unroll
            for (int c = 0; c < 2; ++c) {
                accS[c][p] = __builtin_amdgcn_mfma_f32_16x16x32_bf16(aS[c], bX, accS[c][p], 0, 0, 0);
                accF[c][p] = __builtin_amdgcn_mfma_f32_16x16x32_bf16(aF[c], bR, accF[c][p], 0, 0, 0);
            }
        }
    }
    __syncthreads();   // all xs reads done; safe to alias h

    short* h = xs;
#pragma unroll
    for (int c = 0; c < 2; ++c) {
        int chb = ch0 + c * 16 + quad * 4;
#pragma unroll
        for (int p = 0; p < 4; ++p) {
            int pt = p * 16 + n;
            short4v hv;
#pragma unroll
            for (int r = 0; r < 4; ++r)
                hv[r] = f2bf(fmaxf(accF[c][p][r] + b0s[chb + r], 0.f));
            *(short4v*)&h[pt * HS + chb] = hv;
        }
    }
    __syncthreads();

    // phase 2: accS += h @ w1
    for (int ks = 0; ks < 4; ++ks) {
        int ko = ks * 32 + quad * 8;
        short8 a1[2];
#pragma unroll
        for (int c = 0; c < 2; ++c)
            a1[c] = *(const short8*)(Wt1r + (ch0 + c * 16 + n) * 128 + ko);
#pragma unroll
        for (int p = 0; p < 4; ++p) {
            short8 bh = *(const short8*)&h[(p * 16 + n) * HS + ko];
#pragma unroll
            for (int c = 0; c < 2; ++c)
                accS[c][p] = __builtin_amdgcn_mfma_f32_16x16x32_bf16(a1[c], bh, accS[c][p], 0, 0, 0);
        }
    }

    // epilogue: direct 8B frag stores (batch-local L2 coalesces; WRITE stays ~ideal — r9 measured)
#pragma unroll
    for (int c = 0; c < 2; ++c) {
        int chb = ch0 + c * 16 + quad * 4;
#pragma unroll
        for (int p = 0; p < 4; ++p) {
            int pt = p * 16 + n;
            short4v o;
#pragma unroll
            for (int r = 0; r < 4; ++r)
                o[r] = f2bf(accS[c][p][r] + b1s[chb + r]);
            *(short4v*)(net_out + (t0 + pt) * HID + chb) = o;
        }
    }
}

// ---------- block 0: stage x = pts@Wp+bp (r7 style: thread=column, weights in regs) ----------
// grid (8, 469) x 256: batch = blockIdx.x (XCD affinity)
__global__ __launch_bounds__(256, 4) void k_mblock0(
    const float* __restrict__ pts, const float* __restrict__ Wp, const float* __restrict__ bp,
    const short* __restrict__ Wt0, const short* __restrict__ Wts, const short* __restrict__ Wt1,
    const float* __restrict__ b0, const float* __restrict__ b1, short* __restrict__ net)
{
    __shared__ short xs[PB * XS];
    __shared__ float b0s[HID], b1s[HID];
    int tid = threadIdx.x;
    int b  = blockIdx.x;
    int r0 = blockIdx.y * PB;
    if (tid < 128) { b0s[tid] = b0[tid]; b1s[tid] = b1[tid]; }

    int j = tid & 127, half = tid >> 7;
    int col = half * 128 + j;
    float w0 = Wp[col], w1 = Wp[256 + col], w2 = Wp[512 + col];
    float bb = bp[col];
    for (int p = 0; p < PB; ++p) {
        int tt = r0 + p; if (tt > TPTS - 1) tt = TPTS - 1;   // tail rows: duplicate last point
        const float* pp = pts + (b * TPTS + tt) * 3;
        float v = fmaf(pp[2], w2, fmaf(pp[1], w1, fmaf(pp[0], w0, bb)));
        xs[p * XS + col] = f2bf(v);
    }
    __syncthreads();
    resnet_body(xs, b0s, b1s, Wt0, Wts, Wt1, net, b * NPR + r0);
}

// ---------- blocks 1..4: stage x = [net | pooled], then resnet ----------
// grid (8, 469) x 256: batch = blockIdx.x (XCD affinity — seg slice per batch fits one XCD L2)
__global__ __launch_bounds__(256, 4) void k_mblock(
    const short* __restrict__ net_in, const short* __restrict__ seg,
    const int* __restrict__ i0, const int* __restrict__ i1, const int* __restrict__ i2,
    const short* __restrict__ Wt0, const short* __restrict__ Wts, const short* __restrict__ Wt1,
    const float* __restrict__ b0, const float* __restrict__ b1, short* __restrict__ net_out)
{
    __shared__ short xs[PB * XS];
    __shared__ float b0s[HID], b1s[HID];
    int tid = threadIdx.x;
    int b  = blockIdx.x;
    int r0 = blockIdx.y * PB;
    if (tid < 128) { b0s[tid] = b0[tid]; b1s[tid] = b1[tid]; }

    int pr = tid >> 4;          // row within group of 16 (16 rows per iter)
    int l8 = (tid & 15) * 8;    // short offset of 16B chunk: 0..120
    // prefetch all indices first, then issue all gathers (ILP)
    int a0[4], a1[4], a2[4];
#pragma unroll
    for (int it = 0; it < 4; ++it) {
        int tt = r0 + it * 16 + pr;
        int ttc = tt > TPTS - 1 ? TPTS - 1 : tt;
        int ib = b * TPTS + ttc;
        a0[it] = i0[ib]; a1[it] = i1[ib]; a2[it] = i2[ib];
    }
#pragma unroll
    for (int it = 0; it < 4; ++it) {
        int p = it * 16 + pr;
        int tt = r0 + p;
        // raw net copy (already bf16); wave reads a contiguous 1KB block
        *(short8*)&xs[p * XS + l8] = *(const short8*)(net_in + (b * NPR + tt) * HID + l8);
        // pooled = sum of 3 plane maxima
        short8 s0 = *(const short8*)(seg + ((0 * BATCH + b) * R2 + a0[it]) * HID + l8);
        short8 s1 = *(const short8*)(seg + ((1 * BATCH + b) * R2 + a1[it]) * HID + l8);
        short8 s2 = *(const short8*)(seg + ((2 * BATCH + b) * R2 + a2[it]) * HID + l8);
        short8 pv;
#pragma unroll
        for (int r = 0; r < 8; ++r)
            pv[r] = f2bf(bf2f((unsigned short)s0[r]) + bf2f((unsigned short)s1[r]) + bf2f((unsigned short)s2[r]));
        *(short8*)&xs[p * XS + 128 + l8] = pv;
    }
    __syncthreads();
    resnet_body(xs, b0s, b1s, Wt0, Wts, Wt1, net_out, b * NPR + r0);
}

// ---------- out = (means @ Wc + bc)^T per plane-batch, empty bins -> 0 ----------
// grid (8, 192): batch = blockIdx.x, plane/bin-tile from blockIdx.y
__global__ __launch_bounds__(256) void k_gemmout(
    const short* __restrict__ meanb, const short* __restrict__ Wtc, const float* __restrict__ bc,
    const int* __restrict__ starts, float* __restrict__ out)
{
    __shared__ short bs[64 * HS];      // means bf16 [bin][k]
    __shared__ float tile[128 * 66];   // output f32 [ch][bin]
    __shared__ float bcs[HID];
    __shared__ int   flg[64];
    int tid = threadIdx.x;
    int b = blockIdx.x;
    int plane = blockIdx.y >> 6;
    int pb = plane * BATCH + b;
    int bin0 = (blockIdx.y & 63) * 64;

    if (tid < 128) bcs[tid] = bc[tid];
    if (tid < 64)  flg[tid] = (starts[pb * 4097 + bin0 + tid + 1] > starts[pb * 4097 + bin0 + tid]);
    for (int c8 = tid; c8 < 1024; c8 += 256) {
        int p = c8 >> 4, l = (c8 & 15) * 8;
        *(short8*)&bs[p * HS + l] = *(const short8*)(meanb + (pb * R2 + bin0 + p) * HID + l);
    }
    __syncthreads();

    int lane = tid & 63, wave = tid >> 6;
    int n = lane & 15, quad = lane >> 4;
    int ch0 = wave * 32;
    f32x4 acc[2][4] = {};
    for (int ks = 0; ks < 4; ++ks) {
        int ko = ks * 32 + quad * 8;
        short8 a[2];
#pragma unroll
        for (int c = 0; c < 2; ++c)
            a[c] = *(const short8*)(Wtc + (ch0 + c * 16 + n) * 128 + ko);
#pragma unroll
        for (int p = 0; p < 4; ++p) {
            short8 bh = *(const short8*)&bs[(p * 16 + n) * HS + ko];
#pragma unroll
            for (int c = 0; c < 2; ++c)
                acc[c][p] = __builtin_amdgcn_mfma_f32_16x16x32_bf16(a[c], bh, acc[c][p], 0, 0, 0);
        }
    }
#pragma unroll
    for (int c = 0; c < 2; ++c) {
        int chb = ch0 + c * 16 + quad * 4;
#pragma unroll
        for (int p = 0; p < 4; ++p) {
            int bin = p * 16 + n;
#pragma unroll
            for (int r = 0; r < 4; ++r)
                tile[(chb + r) * 66 + bin] = acc[c][p][r] + bcs[chb + r];
        }
    }
    __syncthreads();

    for (int c4 = tid; c4 < 2048; c4 += 256) {
        int ch = c4 >> 4, b4 = (c4 & 15) * 4;
        float4 o;
        o.x = flg[b4 + 0] ? tile[ch * 66 + b4 + 0] : 0.f;
        o.y = flg[b4 + 1] ? tile[ch * 66 + b4 + 1] : 0.f;
        o.z = flg[b4 + 2] ? tile[ch * 66 + b4 + 2] : 0.f;
        o.w = flg[b4 + 3] ? tile[ch * 66 + b4 + 3] : 0.f;
        *(float4*)(out + (pb * 128 + ch) * R2 + bin0 + b4) = o;
    }
}

extern "C" void kernel_launch(void* const* d_in, const int* in_sizes, int n_in,
                              void* d_out, int out_size, void* d_ws, size_t ws_size,
                              hipStream_t stream) {
    const float* pts  = (const float*)d_in[0];
    const int*   ixz  = (const int*)d_in[1];
    const int*   ixy  = (const int*)d_in[2];
    const int*   iyz  = (const int*)d_in[3];
    const float* Wp   = (const float*)d_in[4];
    const float* bp   = (const float*)d_in[5];
    const float* fc0w = (const float*)d_in[6];
    const float* fc0b = (const float*)d_in[7];
    const float* fc1w = (const float*)d_in[8];
    const float* fc1b = (const float*)d_in[9];
    const float* scw  = (const float*)d_in[10];
    const float* Wc   = (const float*)d_in[11];
    const float* bc   = (const float*)d_in[12];
    float* out = (float*)d_out;

    short* Wt0 = (short*)d_ws;             // 163840
    short* Wts = Wt0 + 163840;             // 163840
    short* Wt1 = Wts + 163840;             // 81920
    short* Wtc = Wt1 + 81920;              // 16384   (total 425984 shorts)
    short* net  = Wtc + 16384;             // 8*30016*128 shorts, bf16 (batch-padded)
    short* segb = net + 30736384;          // 12,582,912 shorts, bf16 (pool max / means)
    int* hist   = (int*)(segb + 12582912); // 98304 (doubles as cursor)
    int* starts = hist + 98304;            // 24*4097
    unsigned short* order = (unsigned short*)(starts + 98328); // 720000

    k_prep<<<dim3(640), 256, 0, stream>>>(fc0w, fc1w, scw, Wc, Wt0, Wts, Wt1, Wtc);
    k_fill4<<<dim3(96), 256, 0, stream>>>((float4*)hist, 0.f, 98304 / 4);
    k_hist<<<dim3((NPTS + 255) / 256), 256, 0, stream>>>(ixz, ixy, iyz, hist);
    k_scan<<<dim3(24), 256, 0, stream>>>(hist, starts, hist);
    k_scatter<<<dim3((NPTS + 255) / 256), 256, 0, stream>>>(ixz, ixy, iyz, hist, order);

    k_mblock0<<<dim3(8, NPR / PB), 256, 0, stream>>>(pts, Wp, bp, Wt0, Wts, Wt1, fc0b, fc1b, net);

    for (int r = 1; r < 5; ++r) {
        k_poolmax<<<dim3(8, 3 * R2 / 4), 256, 0, stream>>>(net, starts, order, segb);
        k_mblock<<<dim3(8, NPR / PB), 256, 0, stream>>>(
            net, segb, ixz, ixy, iyz,
            Wt0 + r * 32768, Wts + r * 32768, Wt1 + r * 16384,
            fc0b + r * 128, fc1b + r * 128, net);
    }

    // segment_mean(net@Wc+bc) == segment_mean(net)@Wc+bc  (bin means, then tiny GEMM)
    k_poolmean<<<dim3(8, 3 * R2 / 4), 256, 0, stream>>>(net, starts, order, segb);
    k_gemmout<<<dim3(8, 3 * 64), 256, 0, stream>>>(segb, Wtc, bc, starts, out);
}